// Round 3
// baseline (305.322 us; speedup 1.0000x reference)
//
#include <hip/hip_runtime.h>
#include <math.h>

#define BATCH 128
#define NPRI  8732
#define CCH   512
#define HH    19
#define NHID  4096
#define FGC   19

typedef unsigned short u16;
typedef __attribute__((ext_vector_type(8))) short bf16x8;
typedef __attribute__((ext_vector_type(4))) float f32x4;

// RNE fp32 -> bf16 (finite values)
__device__ __forceinline__ u16 f2bf(float f) {
  unsigned u = __float_as_uint(f);
  u += 0x7fff + ((u >> 16) & 1);
  return (u16)(u >> 16);
}

// ---------------------------------------------------------------------------
// K1: fused best-prior. One block per batch. Reduce argmax of car score in
// LDS; thread 0 decodes box + writes boxes/valid outputs + crop coords;
// threads 0..18 initialize the fg_cls output rows with b3 (GEMM3 atomically
// accumulates on top of this later in the stream).
// ---------------------------------------------------------------------------
__global__ void k_best(const float* __restrict__ loc,
                       const float* __restrict__ conf,
                       const float* __restrict__ priors,
                       const float* __restrict__ b3,
                       float* __restrict__ out,
                       int4* __restrict__ crop,
                       int* __restrict__ vflag) {
  int b = blockIdx.x;
  int t = threadIdx.x;
  const float* cb = conf + (size_t)b * NPRI * 2;
  float bestS = -INFINITY; int bestN = 0x7fffffff; int car_any = 0;
  for (int i = t; i < NPRI; i += 256) {
    float2 c = *(const float2*)(cb + 2 * i);
    float m = fmaxf(c.x, c.y);
    float e0 = expf(c.x - m), e1 = expf(c.y - m);
    float s = e0 + e1;
    float p0 = e0 / s, p1 = e1 / s;
    bool car = p1 > p0;                 // argmax(probs)==1: strict
    car_any |= (int)car;
    float sc = car ? p1 : -INFINITY;
    if (sc > bestS || (sc == bestS && i < bestN)) { bestS = sc; bestN = i; }
  }
  __shared__ float ls[256]; __shared__ int li[256]; __shared__ int lc[256];
  ls[t] = bestS; li[t] = bestN; lc[t] = car_any;
  __syncthreads();
  for (int off = 128; off > 0; off >>= 1) {
    if (t < off) {
      float s2 = ls[t + off]; int n2 = li[t + off];
      if (s2 > ls[t] || (s2 == ls[t] && n2 < li[t])) { ls[t] = s2; li[t] = n2; }
      lc[t] |= lc[t + off];
    }
    __syncthreads();
  }
  // fg_cls bias init (GEMM3 atomics add onto this)
  if (t < FGC) out[b * FGC + t] = b3[t];
  if (t == 0) {
    int hc = lc[0];
    int bn = hc ? li[0] : 0;            // argmax of all -inf -> 0 (jnp semantics)
    const float* lp = loc + ((size_t)b * NPRI + bn) * 4;
    const float* pp = priors + (size_t)bn * 4;
    float l0 = lp[0], l1 = lp[1], l2 = lp[2], l3 = lp[3];
    float pcx = pp[0], pcy = pp[1], pw = pp[2], ph = pp[3];
    float cx = pcx + (l0 * 0.1f) * pw;
    float cy = pcy + (l1 * 0.1f) * ph;
    float w = pw * expf(l2 * 0.2f);
    float h = ph * expf(l3 * 0.2f);
    float x1 = cx - 0.5f * w;
    float y1 = cy - 0.5f * h;
    float x2 = x1 + w, y2 = y1 + h;     // reference does xy1 + wh
    bool geom = (x2 > x1) && (y2 > y1);
    bool valid = hc && geom;
    float r0, r1, r2, r3;
    if (hc) { r0 = x1; r1 = y1; r2 = x2; r3 = y2; }
    else    { r0 = r1 = r2 = r3 = 0.0f; }
    r0 = fminf(fmaxf(r0, 0.0f), 1.0f);
    r1 = fminf(fmaxf(r1, 0.0f), 1.0f);
    r2 = fminf(fmaxf(r2, 0.0f), 1.0f);
    r3 = fminf(fmaxf(r3, 0.0f), 1.0f);
    float* ob = out + BATCH * FGC;
    ob[b * 4 + 0] = r0; ob[b * 4 + 1] = r1;
    ob[b * 4 + 2] = r2; ob[b * 4 + 3] = r3;
    out[BATCH * FGC + BATCH * 4 + b] = valid ? 1.0f : 0.0f;
    const float stepF = (float)(300.0 / 19.0);
    float q0 = fminf(fmaxf(r0 * 300.0f, 0.0f), 300.0f) / stepF;
    float q1 = fminf(fmaxf(r1 * 300.0f, 0.0f), 300.0f) / stepF;
    float q2 = fminf(fmaxf(r2 * 300.0f, 0.0f), 300.0f) / stepF;
    float q3 = fminf(fmaxf(r3 * 300.0f, 0.0f), 300.0f) / stepF;
    int ix1 = (int)floorf(fminf(fmaxf(q0, 0.0f), 18.0f));
    int iy1 = (int)floorf(fminf(fmaxf(q1, 0.0f), 18.0f));
    int ix2 = (int)floorf(fminf(fmaxf(q2, 0.0f), 18.0f));
    int iy2 = (int)floorf(fminf(fmaxf(q3, 0.0f), 18.0f));
    crop[b] = make_int4(ix1, iy1, ix2, iy2);
    vflag[b] = valid ? 1 : 0;
  }
}

// ---------------------------------------------------------------------------
// K2: crop + global max pool -> bf16 feat.
// Rows y1..y2 of a channel map form a CONTIGUOUS float span [y1*19,(y2+1)*19).
// Read it with aligned float4s, mask x via e%19. Grid: (b, 64-channel group),
// one wave per channel, 16 channels/wave.
// ---------------------------------------------------------------------------
__global__ void k_extract(const float* __restrict__ fin,
                          const int4* __restrict__ crop,
                          const int* __restrict__ vflag,
                          u16* __restrict__ feat) {
  int b = blockIdx.x >> 3;
  int cg = blockIdx.x & 7;
  int wave = threadIdx.x >> 6, lane = threadIdx.x & 63;
  if (!vflag[b]) {
    if (lane == 0) {
      #pragma unroll
      for (int ci = 0; ci < 16; ci++) feat[b * CCH + cg * 64 + ci * 4 + wave] = 0;
    }
    return;
  }
  int4 cr = crop[b];
  int base = cr.y * HH;
  int L = (cr.w - cr.y + 1) * HH;       // contiguous span length
  int a0 = base & ~3;                    // aligned start (rows above y1 masked)
  int offs = base - a0;
  int total = offs + L;
  int nf4 = total >> 2, rem = total & 3;
  int x1 = cr.x, x2 = cr.z;
  #pragma unroll 4
  for (int ci = 0; ci < 16; ci++) {
    int c = cg * 64 + ci * 4 + wave;
    const float* p = fin + (size_t)(b * CCH + c) * (HH * HH) + a0;
    float m = -INFINITY;
    for (int i = lane; i < nf4; i += 64) {
      float4 v = *(const float4*)(p + 4 * i);
      int e = a0 + 4 * i;
      #pragma unroll
      for (int j = 0; j < 4; j++) {
        int ej = e + j;
        int x = ej % HH;
        bool in = (ej >= base) && (x >= x1) && (x <= x2);
        float f = j == 0 ? v.x : (j == 1 ? v.y : (j == 2 ? v.z : v.w));
        m = in ? fmaxf(m, f) : m;
      }
    }
    if (lane < rem) {
      int ej = a0 + 4 * nf4 + lane;
      int x = ej % HH;
      if (ej >= base && x >= x1 && x <= x2) m = fmaxf(m, p[4 * nf4 + lane]);
    }
    #pragma unroll
    for (int off = 32; off > 0; off >>= 1) m = fmaxf(m, __shfl_xor(m, off));
    if (lane == 0) feat[b * CCH + c] = f2bf(m);
  }
}

// ---------------------------------------------------------------------------
// K3: pipelined bf16 MFMA GEMM. A bf16 [128,K], W fp32 [K,4096] converted
// in-register during staging. Block tile 128m x 64n, BK=32, KSPL K-split.
// Double-buffered LDS (one barrier/iter) + register prefetch of next tile:
// global latency overlaps MFMA. float4 W loads (256B contig per quarter-wave).
// ---------------------------------------------------------------------------
template <int KSPL>
__global__ __launch_bounds__(256, 2) void k_mfma(const u16* __restrict__ A,
                                                 const float* __restrict__ W,
                                                 float* __restrict__ part, int K) {
  const int N = NHID, BK = 32, ST = 40;  // LDS row stride (bf16), 16B-aligned
  __shared__ u16 As[2][128 * ST];        // 2 x 10240 B
  __shared__ u16 Bs[2][64 * ST];         // 2 x 5120 B
  int nb = blockIdx.x, ks = blockIdx.y;
  int Kper = K / KSPL, k0b = ks * Kper;
  int t = threadIdx.x, lane = t & 63, wave = t >> 6;
  int q = lane >> 4, r = lane & 15;
  int wm = (wave & 1) * 64, wn = (wave >> 1) * 32, n0 = nb * 64;

  int am = t >> 1, ah = (t & 1) * 16;    // A loader: row, 16-elem half
  int kp = t >> 4, n4 = (t & 15) * 4;    // W loader: k-pair 2kp, 4 contig n

  const u16* aptr = A + (size_t)am * K + k0b + ah;
  const float* wptr = W + (size_t)(k0b + 2 * kp) * N + n0 + n4;

  // prologue: load tile 0
  uint4 a0 = *(const uint4*)aptr;
  uint4 a1 = *(const uint4*)(aptr + 8);
  float4 w0 = *(const float4*)wptr;
  float4 w1 = *(const float4*)(wptr + N);

  f32x4 acc[4][2];
  #pragma unroll
  for (int i = 0; i < 4; i++)
    #pragma unroll
    for (int j = 0; j < 2; j++) {
      acc[i][j].x = 0.f; acc[i][j].y = 0.f; acc[i][j].z = 0.f; acc[i][j].w = 0.f;
    }

  // store tile 0 into buffer 0
  *(uint4*)&As[0][am * ST + ah]     = a0;
  *(uint4*)&As[0][am * ST + ah + 8] = a1;
  {
    unsigned pk0 = (unsigned)f2bf(w0.x) | ((unsigned)f2bf(w1.x) << 16);
    unsigned pk1 = (unsigned)f2bf(w0.y) | ((unsigned)f2bf(w1.y) << 16);
    unsigned pk2 = (unsigned)f2bf(w0.z) | ((unsigned)f2bf(w1.z) << 16);
    unsigned pk3 = (unsigned)f2bf(w0.w) | ((unsigned)f2bf(w1.w) << 16);
    *(unsigned*)&Bs[0][(n4 + 0) * ST + 2 * kp] = pk0;
    *(unsigned*)&Bs[0][(n4 + 1) * ST + 2 * kp] = pk1;
    *(unsigned*)&Bs[0][(n4 + 2) * ST + 2 * kp] = pk2;
    *(unsigned*)&Bs[0][(n4 + 3) * ST + 2 * kp] = pk3;
  }

  int nIter = Kper / BK;
  for (int it = 0; it < nIter; it++) {
    __syncthreads();                     // buf(it&1) ready; prev reads done
    int cur = it & 1;
    bool more = (it + 1 < nIter);
    if (more) {                          // prefetch next tile (in flight during MFMA)
      aptr += BK;
      wptr += (size_t)BK * N;
      a0 = *(const uint4*)aptr;
      a1 = *(const uint4*)(aptr + 8);
      w0 = *(const float4*)wptr;
      w1 = *(const float4*)(wptr + N);
    }
    bf16x8 af[4], bfr[2];
    #pragma unroll
    for (int i = 0; i < 4; i++)
      af[i] = *(const bf16x8*)&As[cur][(wm + 16 * i + r) * ST + q * 8];
    #pragma unroll
    for (int j = 0; j < 2; j++)
      bfr[j] = *(const bf16x8*)&Bs[cur][(wn + 16 * j + r) * ST + q * 8];
    #pragma unroll
    for (int i = 0; i < 4; i++)
      #pragma unroll
      for (int j = 0; j < 2; j++)
        acc[i][j] = __builtin_amdgcn_mfma_f32_16x16x32_bf16(af[i], bfr[j],
                                                            acc[i][j], 0, 0, 0);
    if (more) {                          // stage next tile into the other buffer
      int nxt = cur ^ 1;
      *(uint4*)&As[nxt][am * ST + ah]     = a0;
      *(uint4*)&As[nxt][am * ST + ah + 8] = a1;
      unsigned pk0 = (unsigned)f2bf(w0.x) | ((unsigned)f2bf(w1.x) << 16);
      unsigned pk1 = (unsigned)f2bf(w0.y) | ((unsigned)f2bf(w1.y) << 16);
      unsigned pk2 = (unsigned)f2bf(w0.z) | ((unsigned)f2bf(w1.z) << 16);
      unsigned pk3 = (unsigned)f2bf(w0.w) | ((unsigned)f2bf(w1.w) << 16);
      *(unsigned*)&Bs[nxt][(n4 + 0) * ST + 2 * kp] = pk0;
      *(unsigned*)&Bs[nxt][(n4 + 1) * ST + 2 * kp] = pk1;
      *(unsigned*)&Bs[nxt][(n4 + 2) * ST + 2 * kp] = pk2;
      *(unsigned*)&Bs[nxt][(n4 + 3) * ST + 2 * kp] = pk3;
    }
  }

  // epilogue: C row = wm+16i+q*4+reg, col = n0+wn+16j+r (verified R2)
  float* dst = part + (size_t)ks * (BATCH * N);
  #pragma unroll
  for (int i = 0; i < 4; i++)
    #pragma unroll
    for (int j = 0; j < 2; j++) {
      int col = n0 + wn + 16 * j + r;
      #pragma unroll
      for (int reg = 0; reg < 4; reg++) {
        int row = wm + 16 * i + q * 4 + reg;
        dst[(size_t)row * N + col] = acc[i][j][reg];
      }
    }
}

// ---------------------------------------------------------------------------
// K4: sum KSPL partials + bias + relu; fp32 or bf16 output
// ---------------------------------------------------------------------------
template <int KSPL, bool BF16OUT>
__global__ void k_finalize(const float* __restrict__ part,
                           const float* __restrict__ bias,
                           float* __restrict__ outf,
                           u16* __restrict__ outb) {
  int idx = (blockIdx.x * 256 + threadIdx.x) * 4;
  float4 s = *(const float4*)(part + idx);
  #pragma unroll
  for (int p = 1; p < KSPL; p++) {
    float4 v = *(const float4*)(part + (size_t)p * (BATCH * NHID) + idx);
    s.x += v.x; s.y += v.y; s.z += v.z; s.w += v.w;
  }
  float4 bv = *(const float4*)(bias + (idx & (NHID - 1)));
  s.x = fmaxf(s.x + bv.x, 0.0f); s.y = fmaxf(s.y + bv.y, 0.0f);
  s.z = fmaxf(s.z + bv.z, 0.0f); s.w = fmaxf(s.w + bv.w, 0.0f);
  if (BF16OUT) {
    ushort4 o;
    o.x = f2bf(s.x); o.y = f2bf(s.y); o.z = f2bf(s.z); o.w = f2bf(s.w);
    *(ushort4*)(outb + idx) = o;
  } else {
    *(float4*)(outf + idx) = s;
  }
}

// ---------------------------------------------------------------------------
// K5: final projection via atomics. 32 blocks, each owns a 128-k chunk of w3
// staged in LDS; thread handles (m = t&127, k-half = t>>7); atomicAdd into
// out (pre-initialized with b3 by k_best).
// ---------------------------------------------------------------------------
__global__ void k_gemm3a(const float* __restrict__ h2,
                         const float* __restrict__ w3,
                         float* __restrict__ out) {
  int kc = blockIdx.x;                  // 32 chunks of 128 k
  int t = threadIdx.x;
  __shared__ float wl[128 * FGC];       // 9728 B
  for (int i = t; i < 128 * FGC; i += 256) wl[i] = w3[kc * 128 * FGC + i];
  __syncthreads();
  int m = t & 127, half = t >> 7;
  const float* hp = h2 + (size_t)m * NHID + kc * 128 + half * 64;
  float acc[FGC];
  #pragma unroll
  for (int j = 0; j < FGC; j++) acc[j] = 0.0f;
  for (int k = 0; k < 64; k++) {
    float hv = hp[k];
    const float* wp = &wl[(half * 64 + k) * FGC];   // wave-uniform: broadcast
    #pragma unroll
    for (int j = 0; j < FGC; j++) acc[j] += hv * wp[j];
  }
  #pragma unroll
  for (int j = 0; j < FGC; j++) atomicAdd(&out[m * FGC + j], acc[j]);
}

// ---------------------------------------------------------------------------
extern "C" void kernel_launch(void* const* d_in, const int* in_sizes, int n_in,
                              void* d_out, int out_size, void* d_ws, size_t ws_size,
                              hipStream_t stream) {
  const float* loc      = (const float*)d_in[0];
  const float* conf     = (const float*)d_in[1];
  const float* priors   = (const float*)d_in[2];
  const float* features = (const float*)d_in[3];
  const float* w1 = (const float*)d_in[4];
  const float* b1 = (const float*)d_in[5];
  const float* w2 = (const float*)d_in[6];
  const float* b2 = (const float*)d_in[7];
  const float* w3 = (const float*)d_in[8];
  const float* b3 = (const float*)d_in[9];
  float* out = (float*)d_out;           // [128*19 fg][128*4 boxes][128 valid]

  char* ws = (char*)d_ws;
  float* part  = (float*)ws;                                    // 16 MB
  float* h2    = (float*)(ws + (size_t)16 * 1024 * 1024);       // 2 MB
  u16*   featb = (u16*)(ws + (size_t)18 * 1024 * 1024);         // 128 KB
  u16*   h1b   = (u16*)(ws + (size_t)18 * 1024 * 1024 + 512 * 1024);  // 1 MB
  int4*  crop  = (int4*)(ws + (size_t)20 * 1024 * 1024);
  int*   vfl   = (int*)(crop + BATCH);

  k_best<<<BATCH, 256, 0, stream>>>(loc, conf, priors, b3, out, crop, vfl);
  k_extract<<<BATCH * 8, 256, 0, stream>>>(features, crop, vfl, featb);
  k_mfma<4><<<dim3(64, 4), 256, 0, stream>>>(featb, w1, part, 512);
  k_finalize<4, true><<<512, 256, 0, stream>>>(part, b1, nullptr, h1b);
  k_mfma<8><<<dim3(64, 8), 256, 0, stream>>>(h1b, w2, part, 4096);
  k_finalize<8, false><<<512, 256, 0, stream>>>(part, b2, h2, nullptr);
  k_gemm3a<<<32, 256, 0, stream>>>(h2, w3, out);
}

// Round 4
// 261.062 us; speedup vs baseline: 1.1695x; 1.1695x over previous
//
#include <hip/hip_runtime.h>
#include <hip/hip_bf16.h>
#include <math.h>

#define BATCH 128
#define NPRI  8732
#define CCH   512
#define HH    19
#define NHID  4096
#define FGC   19

typedef unsigned short u16;
typedef __attribute__((ext_vector_type(8))) short bf16x8;
typedef __attribute__((ext_vector_type(4))) float f32x4;

// RNE fp32 -> bf16 (finite values)
__device__ __forceinline__ u16 f2bf(float f) {
  unsigned u = __float_as_uint(f);
  u += 0x7fff + ((u >> 16) & 1);
  return (u16)(u >> 16);
}

// ---------------------------------------------------------------------------
// K1a: per-(batch, quarter) partial argmax of car score  (R2 version)
// ---------------------------------------------------------------------------
__global__ void k_best_partial(const float* __restrict__ conf,
                               float* __restrict__ cs, int* __restrict__ ci,
                               int* __restrict__ cc) {
  int blk = blockIdx.x;
  int b = blk >> 2, chunk = blk & 3;
  int n0 = chunk * 2183;
  int t = threadIdx.x;
  const float* cb = conf + (size_t)b * NPRI * 2;
  float bestS = -INFINITY; int bestN = 0x7fffffff; int car_any = 0;
  for (int i = n0 + t; i < n0 + 2183; i += 256) {
    float c0 = cb[2 * i], c1 = cb[2 * i + 1];
    float m = fmaxf(c0, c1);
    float e0 = expf(c0 - m), e1 = expf(c1 - m);
    float s = e0 + e1;
    float p0 = e0 / s, p1 = e1 / s;
    bool car = p1 > p0;
    car_any |= (int)car;
    float sc = car ? p1 : -INFINITY;
    if (sc > bestS || (sc == bestS && i < bestN)) { bestS = sc; bestN = i; }
  }
  __shared__ float ls[256]; __shared__ int li[256]; __shared__ int lc[256];
  ls[t] = bestS; li[t] = bestN; lc[t] = car_any;
  __syncthreads();
  for (int off = 128; off > 0; off >>= 1) {
    if (t < off) {
      float s2 = ls[t + off]; int n2 = li[t + off];
      if (s2 > ls[t] || (s2 == ls[t] && n2 < li[t])) { ls[t] = s2; li[t] = n2; }
      lc[t] |= lc[t + off];
    }
    __syncthreads();
  }
  if (t == 0) { cs[blk] = ls[0]; ci[blk] = li[0]; cc[blk] = lc[0]; }
}

// ---------------------------------------------------------------------------
// K1b: combine + decode + outputs + crop coords  (R2 version)
// ---------------------------------------------------------------------------
__global__ void k_best_final(const float* __restrict__ loc,
                             const float* __restrict__ priors,
                             const float* __restrict__ cs,
                             const int* __restrict__ ci,
                             const int* __restrict__ cc,
                             float* __restrict__ out_boxes,
                             float* __restrict__ out_valid,
                             int4* __restrict__ crop,
                             int* __restrict__ vflag) {
  int b = threadIdx.x;
  if (b >= BATCH) return;
  float bs = -INFINITY; int bn = 0; int hc = 0;
  #pragma unroll
  for (int p = 0; p < 4; p++) {
    float s = cs[b * 4 + p]; int n = ci[b * 4 + p];
    hc |= cc[b * 4 + p];
    if (s > bs) { bs = s; bn = n; }
  }
  const float* lp = loc + ((size_t)b * NPRI + bn) * 4;
  const float* pp = priors + (size_t)bn * 4;
  float l0 = lp[0], l1 = lp[1], l2 = lp[2], l3 = lp[3];
  float pcx = pp[0], pcy = pp[1], pw = pp[2], ph = pp[3];
  float cx = pcx + (l0 * 0.1f) * pw;
  float cy = pcy + (l1 * 0.1f) * ph;
  float w = pw * expf(l2 * 0.2f);
  float h = ph * expf(l3 * 0.2f);
  float x1 = cx - 0.5f * w;
  float y1 = cy - 0.5f * h;
  float x2 = x1 + w, y2 = y1 + h;
  bool geom = (x2 > x1) && (y2 > y1);
  bool valid = hc && geom;
  float r0, r1, r2, r3;
  if (hc) { r0 = x1; r1 = y1; r2 = x2; r3 = y2; }
  else    { r0 = r1 = r2 = r3 = 0.0f; }
  r0 = fminf(fmaxf(r0, 0.0f), 1.0f);
  r1 = fminf(fmaxf(r1, 0.0f), 1.0f);
  r2 = fminf(fmaxf(r2, 0.0f), 1.0f);
  r3 = fminf(fmaxf(r3, 0.0f), 1.0f);
  out_boxes[b * 4 + 0] = r0; out_boxes[b * 4 + 1] = r1;
  out_boxes[b * 4 + 2] = r2; out_boxes[b * 4 + 3] = r3;
  out_valid[b] = valid ? 1.0f : 0.0f;
  const float stepF = (float)(300.0 / 19.0);
  float q0 = fminf(fmaxf(r0 * 300.0f, 0.0f), 300.0f) / stepF;
  float q1 = fminf(fmaxf(r1 * 300.0f, 0.0f), 300.0f) / stepF;
  float q2 = fminf(fmaxf(r2 * 300.0f, 0.0f), 300.0f) / stepF;
  float q3 = fminf(fmaxf(r3 * 300.0f, 0.0f), 300.0f) / stepF;
  int ix1 = (int)floorf(fminf(fmaxf(q0, 0.0f), 18.0f));
  int iy1 = (int)floorf(fminf(fmaxf(q1, 0.0f), 18.0f));
  int ix2 = (int)floorf(fminf(fmaxf(q2, 0.0f), 18.0f));
  int iy2 = (int)floorf(fminf(fmaxf(q3, 0.0f), 18.0f));
  crop[b] = make_int4(ix1, iy1, ix2, iy2);
  vflag[b] = valid ? 1 : 0;
}

// ---------------------------------------------------------------------------
// K2: crop + global max pool -> bf16 feat  (R2 version)
// ---------------------------------------------------------------------------
__global__ void k_extract(const float* __restrict__ fin,
                          const int4* __restrict__ crop,
                          const int* __restrict__ vflag,
                          u16* __restrict__ feat) {
  int blk = blockIdx.x;
  int b = blk >> 7;
  int tile = blk & 127;
  int wave = threadIdx.x >> 6;
  int lane = threadIdx.x & 63;
  int c = tile * 4 + wave;
  if (!vflag[b]) {
    if (lane == 0) feat[b * CCH + c] = 0;
    return;
  }
  int4 cr = crop[b];
  int wcnt = cr.z - cr.x + 1;
  int cnt = wcnt * (cr.w - cr.y + 1);
  const float* p = fin + (size_t)(b * CCH + c) * (HH * HH);
  float m = -INFINITY;
  for (int i = lane; i < cnt; i += 64) {
    int yy = cr.y + i / wcnt;
    int xx = cr.x + i % wcnt;
    m = fmaxf(m, p[yy * HH + xx]);
  }
  #pragma unroll
  for (int off = 32; off > 0; off >>= 1) m = fmaxf(m, __shfl_xor(m, off));
  if (lane == 0) feat[b * CCH + c] = f2bf(m);
}

// ---------------------------------------------------------------------------
// K3: bf16 MFMA GEMM (R2 structure: single-buffer, 2 barriers/iter).
// ONLY change vs R2: W staging = 2x float4 per thread (contiguous 256B per
// 16-lane group) instead of 8 strided scalar dwords.
// ---------------------------------------------------------------------------
template <int KSPL>
__global__ __launch_bounds__(256) void k_mfma(const u16* __restrict__ A,
                                              const float* __restrict__ W,
                                              float* __restrict__ part, int K) {
  const int N = 4096;
  const int BK = 32;
  int nb = blockIdx.x;             // 64 n-tiles of 64
  int ks = blockIdx.y;
  int Kper = K / KSPL;
  int k0b = ks * Kper;
  int t = threadIdx.x;
  int lane = t & 63, wave = t >> 6;
  int q = lane >> 4, r = lane & 15;

  __shared__ u16 As[128 * 40];     // 10240 B, row stride 40 (80 B)
  __shared__ u16 Bs[64 * 40];      // 5120 B

  int wm = (wave & 1) * 64;
  int wn = (wave >> 1) * 32;
  int n0 = nb * 64;

  f32x4 acc[4][2];
  #pragma unroll
  for (int i = 0; i < 4; i++)
    #pragma unroll
    for (int j = 0; j < 2; j++) {
      acc[i][j].x = 0.f; acc[i][j].y = 0.f; acc[i][j].z = 0.f; acc[i][j].w = 0.f;
    }

  // staging assignments
  int am = t >> 1, ah = (t & 1) * 16;  // A: row, 16-elem half
  int kp = t >> 4;                     // W: k-pair index (0..15)
  int n4 = (t & 15) * 4;               // W: 4 contiguous n

  for (int k0 = k0b; k0 < k0b + Kper; k0 += BK) {
    // --- global loads (issued before barrier) ---
    const u16* asrc = A + (size_t)am * K + k0 + ah;
    uint4 a0 = *(const uint4*)asrc;
    uint4 a1 = *(const uint4*)(asrc + 8);
    const float* wsrc = W + (size_t)(k0 + 2 * kp) * N + n0 + n4;
    float4 w0 = *(const float4*)wsrc;        // k even
    float4 w1 = *(const float4*)(wsrc + N);  // k odd
    __syncthreads();                 // previous iter's readers done
    // --- LDS stores ---
    *(uint4*)&As[am * 40 + ah]     = a0;
    *(uint4*)&As[am * 40 + ah + 8] = a1;
    {
      unsigned pk0 = (unsigned)f2bf(w0.x) | ((unsigned)f2bf(w1.x) << 16);
      unsigned pk1 = (unsigned)f2bf(w0.y) | ((unsigned)f2bf(w1.y) << 16);
      unsigned pk2 = (unsigned)f2bf(w0.z) | ((unsigned)f2bf(w1.z) << 16);
      unsigned pk3 = (unsigned)f2bf(w0.w) | ((unsigned)f2bf(w1.w) << 16);
      *(unsigned*)&Bs[(n4 + 0) * 40 + 2 * kp] = pk0;
      *(unsigned*)&Bs[(n4 + 1) * 40 + 2 * kp] = pk1;
      *(unsigned*)&Bs[(n4 + 2) * 40 + 2 * kp] = pk2;
      *(unsigned*)&Bs[(n4 + 3) * 40 + 2 * kp] = pk3;
    }
    __syncthreads();
    // --- fragments + MFMA ---
    bf16x8 af[4], bfr[2];
    #pragma unroll
    for (int i = 0; i < 4; i++)
      af[i] = *(const bf16x8*)&As[(wm + 16 * i + r) * 40 + q * 8];
    #pragma unroll
    for (int j = 0; j < 2; j++)
      bfr[j] = *(const bf16x8*)&Bs[(wn + 16 * j + r) * 40 + q * 8];
    #pragma unroll
    for (int i = 0; i < 4; i++)
      #pragma unroll
      for (int j = 0; j < 2; j++)
        acc[i][j] = __builtin_amdgcn_mfma_f32_16x16x32_bf16(af[i], bfr[j],
                                                            acc[i][j], 0, 0, 0);
  }

  // epilogue: C row = wm+16i+q*4+reg, col = n0+wn+16j+r (verified R2)
  float* dst = part + (size_t)ks * (BATCH * N);
  #pragma unroll
  for (int i = 0; i < 4; i++)
    #pragma unroll
    for (int j = 0; j < 2; j++) {
      int col = n0 + wn + 16 * j + r;
      #pragma unroll
      for (int reg = 0; reg < 4; reg++) {
        int row = wm + 16 * i + q * 4 + reg;
        dst[(size_t)row * N + col] = acc[i][j][reg];
      }
    }
}

// ---------------------------------------------------------------------------
// K4: sum KSPL partials + bias + relu; fp32 or bf16 output  (R2 version)
// ---------------------------------------------------------------------------
template <int KSPL, bool BF16OUT>
__global__ void k_finalize(const float* __restrict__ part,
                           const float* __restrict__ bias,
                           float* __restrict__ outf,
                           u16* __restrict__ outb) {
  int idx = (blockIdx.x * 256 + threadIdx.x) * 4;
  float4 s = *(const float4*)(part + idx);
  #pragma unroll
  for (int p = 1; p < KSPL; p++) {
    float4 v = *(const float4*)(part + (size_t)p * (BATCH * NHID) + idx);
    s.x += v.x; s.y += v.y; s.z += v.z; s.w += v.w;
  }
  float4 bv = *(const float4*)(bias + (idx & (NHID - 1)));
  s.x = fmaxf(s.x + bv.x, 0.0f); s.y = fmaxf(s.y + bv.y, 0.0f);
  s.z = fmaxf(s.z + bv.z, 0.0f); s.w = fmaxf(s.w + bv.w, 0.0f);
  if (BF16OUT) {
    ushort4 o;
    o.x = f2bf(s.x); o.y = f2bf(s.y); o.z = f2bf(s.z); o.w = f2bf(s.w);
    *(ushort4*)(outb + idx) = o;
  } else {
    *(float4*)(outf + idx) = s;
  }
}

// ---------------------------------------------------------------------------
// K5: final projection partials  (R2 version)
// ---------------------------------------------------------------------------
__global__ void k_gemm3p(const float* __restrict__ h2,
                         const float* __restrict__ w3,
                         float* __restrict__ part3) {
  int kc = blockIdx.x;             // 128 chunks of 32 k
  int t = threadIdx.x;             // 128 threads, m = t
  __shared__ float wl[32 * FGC];
  for (int i = t; i < 32 * FGC; i += 128) wl[i] = w3[kc * 32 * FGC + i];
  __syncthreads();
  const float* hp = h2 + (size_t)t * NHID + kc * 32;
  float acc[FGC];
  #pragma unroll
  for (int j = 0; j < FGC; j++) acc[j] = 0.0f;
  for (int k = 0; k < 32; k++) {
    float hv = hp[k];
    const float* wp = &wl[k * FGC];
    #pragma unroll
    for (int j = 0; j < FGC; j++) acc[j] += hv * wp[j];
  }
  float* dst = part3 + (size_t)kc * (BATCH * FGC) + t * FGC;
  #pragma unroll
  for (int j = 0; j < FGC; j++) dst[j] = acc[j];
}

__global__ void k_fin3(const float* __restrict__ part3,
                       const float* __restrict__ b3,
                       float* __restrict__ out) {
  int j = blockIdx.x * 256 + threadIdx.x;
  if (j >= BATCH * FGC) return;
  float s = 0.0f;
  for (int p = 0; p < 128; p++) s += part3[(size_t)p * (BATCH * FGC) + j];
  out[j] = s + b3[j % FGC];
}

// ---------------------------------------------------------------------------
extern "C" void kernel_launch(void* const* d_in, const int* in_sizes, int n_in,
                              void* d_out, int out_size, void* d_ws, size_t ws_size,
                              hipStream_t stream) {
  const float* loc      = (const float*)d_in[0];
  const float* conf     = (const float*)d_in[1];
  const float* priors   = (const float*)d_in[2];
  const float* features = (const float*)d_in[3];
  const float* w1 = (const float*)d_in[4];
  const float* b1 = (const float*)d_in[5];
  const float* w2 = (const float*)d_in[6];
  const float* b2 = (const float*)d_in[7];
  const float* w3 = (const float*)d_in[8];
  const float* b3 = (const float*)d_in[9];
  float* out = (float*)d_out;      // [128*19 fg][128*4 boxes][128 valid]

  char* ws = (char*)d_ws;
  float* part  = (float*)ws;                                    // 16 MB
  float* part3 = (float*)(ws + (size_t)16 * 1024 * 1024);       // 1.25 MB
  float* h2    = (float*)(ws + (size_t)18 * 1024 * 1024);       // 2 MB
  u16*   featb = (u16*)(ws + (size_t)20 * 1024 * 1024);         // 128 KB
  u16*   h1b   = (u16*)(ws + (size_t)20 * 1024 * 1024 + 256 * 1024);  // 1 MB
  float* cs    = (float*)(ws + (size_t)21 * 1024 * 1024);
  int*   ci    = (int*)(cs + 512);
  int*   cc    = ci + 512;
  int4*  crop  = (int4*)(cc + 512);
  int*   vfl   = (int*)(crop + BATCH);

  k_best_partial<<<512, 256, 0, stream>>>(conf, cs, ci, cc);
  k_best_final<<<1, 128, 0, stream>>>(loc, priors, cs, ci, cc,
                                      out + BATCH * FGC,
                                      out + BATCH * FGC + BATCH * 4, crop, vfl);
  k_extract<<<BATCH * (CCH / 4), 256, 0, stream>>>(features, crop, vfl, featb);
  k_mfma<4><<<dim3(64, 4), 256, 0, stream>>>(featb, w1, part, 512);
  k_finalize<4, true><<<512, 256, 0, stream>>>(part, b1, nullptr, h1b);
  k_mfma<8><<<dim3(64, 8), 256, 0, stream>>>(h1b, w2, part, 4096);
  k_finalize<8, false><<<512, 256, 0, stream>>>(part, b2, h2, nullptr);
  k_gemm3p<<<128, 128, 0, stream>>>(h2, w3, part3);
  k_fin3<<<10, 256, 0, stream>>>(part3, b3, out);
}